// Round 18
// baseline (49.589 us; speedup 1.0000x reference)
//
#include <hip/hip_runtime.h>

#define B_ 2
#define N_ 16384
#define M_ 8192
#define CH 2                      // scan chunks per block (2*256 = 512 cols)

typedef float f32x4 __attribute__((ext_vector_type(4)));
typedef float f32x16 __attribute__((ext_vector_type(16)));
typedef short s16x8 __attribute__((ext_vector_type(8)));

__device__ inline float min3f(float a, float b, float c) {
    float d;
    asm("v_min3_f32 %0, %1, %2, %3" : "=v"(d) : "v"(a), "v"(b), "v"(c));
    return d;
}

// ---- DPP 32-lane min reduction (VALU pipe — no DS/shuffle traffic) ----
// R17-verified (absmax 0.0). Valid at lanes 31 and 63 after shr1/2/4/8+bcast15.
__device__ inline float dpp_min_step(float v, const int ctrl) {
    int vi = __float_as_int(v);
    int s;
    switch (ctrl) {   // builtin requires literal ctrl
        case 0x111: s = __builtin_amdgcn_update_dpp(vi, vi, 0x111, 0xf, 0xf, false); break;
        case 0x112: s = __builtin_amdgcn_update_dpp(vi, vi, 0x112, 0xf, 0xf, false); break;
        case 0x114: s = __builtin_amdgcn_update_dpp(vi, vi, 0x114, 0xf, 0xf, false); break;
        case 0x118: s = __builtin_amdgcn_update_dpp(vi, vi, 0x118, 0xf, 0xf, false); break;
        default:    s = __builtin_amdgcn_update_dpp(vi, vi, 0x142, 0xf, 0xf, false); break;
    }
    return fminf(v, __int_as_float(s));
}
__device__ inline float redmin32_dpp(float v) {
    v = dpp_min_step(v, 0x111);   // row_shr:1
    v = dpp_min_step(v, 0x112);   // row_shr:2
    v = dpp_min_step(v, 0x114);   // row_shr:4
    v = dpp_min_step(v, 0x118);   // row_shr:8
    v = dpp_min_step(v, 0x142);   // row_bcast:15
    return v;                     // valid at lanes 31 and 63
}

// RNE f32 -> bf16 (bits)
__device__ inline unsigned short f2bf(float f) {
    unsigned int u = __float_as_uint(f);
    u += 0x7FFFu + ((u >> 16) & 1u);
    return (unsigned short)(u >> 16);
}
__device__ inline float bf2f(unsigned short h) {
    return __uint_as_float(((unsigned int)h) << 16);
}
// 2-way bf16 split: v ~= h + m, residual ~2^-18 rel
__device__ inline void split2(float v, unsigned short& hb, unsigned short& mb) {
    hb = f2bf(v);
    mb = f2bf(v - bf2f(hb));
}

#define ONE_BF ((short)0x3F80)

// K=16 slot maps — verbatim from the ROUND-12/16/17 VERIFIED kernels
__device__ inline void buildA2(float x0, float x1, float x2,
                               s16x8& q0, s16x8& q1) {
    float sq = fmaf(x0, x0, fmaf(x1, x1, x2 * x2));
    unsigned short uh[3], um[3], sh, sm;
    split2(-2.f * x0, uh[0], um[0]);
    split2(-2.f * x1, uh[1], um[1]);
    split2(-2.f * x2, uh[2], um[2]);
    split2(sq, sh, sm);
    q0 = (s16x8){(short)uh[0], (short)uh[1], (short)uh[2], (short)uh[0],
                 (short)uh[1], (short)uh[2], (short)um[0], (short)um[1]};
    q1 = (s16x8){(short)um[2], (short)um[0], (short)um[1], (short)um[2],
                 (short)sh, (short)sm, ONE_BF, ONE_BF};
}
__device__ inline void buildB2(float y0, float y1, float y2,
                               s16x8& q0, s16x8& q1) {
    float sq = fmaf(y0, y0, fmaf(y1, y1, y2 * y2));
    unsigned short yh[3], ym[3], sh, sm;
    split2(y0, yh[0], ym[0]);
    split2(y1, yh[1], ym[1]);
    split2(y2, yh[2], ym[2]);
    split2(sq, sh, sm);
    q0 = (s16x8){(short)yh[0], (short)yh[1], (short)yh[2], (short)ym[0],
                 (short)ym[1], (short)ym[2], (short)yh[0], (short)yh[1]};
    q1 = (s16x8){(short)yh[2], (short)ym[0], (short)ym[1], (short)ym[2],
                 ONE_BF, ONE_BF, (short)sh, (short)sm};
}

// ---------------- block reductions (4 waves, shared scratch passed in) -------

__device__ inline float blk_reduce_max(float v, float* red) {
    #pragma unroll
    for (int off = 32; off; off >>= 1) v = fmaxf(v, __shfl_xor(v, off));
    int wid = threadIdx.x >> 6;
    int lane = threadIdx.x & 63;
    if (lane == 0) red[wid] = v;
    __syncthreads();
    if (wid == 0) {
        v = (lane < 4) ? red[lane] : -3.402823466e38f;
        #pragma unroll
        for (int off = 32; off; off >>= 1) v = fmaxf(v, __shfl_xor(v, off));
        if (lane == 0) red[0] = v;
    }
    __syncthreads();
    v = red[0];
    __syncthreads();
    return v;
}

__device__ inline float blk_reduce_sum(float v, float* red) {
    #pragma unroll
    for (int off = 32; off; off >>= 1) v += __shfl_xor(v, off);
    int wid = threadIdx.x >> 6;
    int lane = threadIdx.x & 63;
    if (lane == 0) red[wid] = v;
    __syncthreads();
    if (wid == 0) {
        v = (lane < 4) ? red[lane] : 0.0f;
        #pragma unroll
        for (int off = 32; off; off >>= 1) v += __shfl_xor(v, off);
        if (lane == 0) red[0] = v;
    }
    __syncthreads();
    v = red[0];
    __syncthreads();
    return v;
}

// ---------------- kernels ----------------

// grid 192 blocks — R12/R16/R17-verbatim init + ctr/acc zeroing.
__global__ __launch_bounds__(256) void init_ws(const float* __restrict__ wts,
                                               const float* __restrict__ p1,
                                               const float* __restrict__ p2,
                                               unsigned int* min1, unsigned int* min2,
                                               float* __restrict__ wmax_part,
                                               unsigned int* __restrict__ ctr,
                                               s16x8* __restrict__ Afrag,
                                               s16x8* __restrict__ Bfrag,
                                               float* out) {
    int j = blockIdx.x * 256 + threadIdx.x;   // [0, B*N + B*M)
    if (j < 256) ctr[j] = 0u;                 // cntF @160, acc @168
    if (j == 0) out[0] = 0.0f;
    if (j < B_ * N_) {
        min1[j] = 0x7F7FFFFFu;                // FLT_MAX bits
        float v = wts[j];
        #pragma unroll
        for (int off = 32; off; off >>= 1) v = fmaxf(v, __shfl_xor(v, off));
        if ((j & 63) == 0) wmax_part[j >> 6] = v;   // 512 wave partials

        int b = j >> 14, n = j & (N_ - 1);
        const float* px = p1 + (size_t)j * 3;
        s16x8 q0, q1;
        buildA2(px[0], px[1], px[2], q0, q1);
        Afrag[((size_t)b * 2 + 0) * N_ + n] = q0;
        Afrag[((size_t)b * 2 + 1) * N_ + n] = q1;
    } else {
        int k = j - B_ * N_;                  // [0, B*M)
        min2[k] = 0x7F7FFFFFu;
        int b = k >> 13, m = k & (M_ - 1);
        const float* py = p2 + (size_t)k * 3;
        s16x8 q0, q1;
        buildB2(py[0], py[1], py[2], q0, q1);
        Bfrag[((size_t)b * 2 + 0) * M_ + m] = q0;
        Bfrag[((size_t)b * 2 + 1) * M_ + m] = q1;
    }
}

// ROUND-18: R17's verified chamfer with LDS STAGING DELETED.
// Theory: Bfrag (0.5MB) is fully L2-resident — staging it through LDS is
// pure overhead (guide lesson: never LDS-stage what L2 fits; m168->m169 was
// +26% for the same change in attention). R17's remaining structure per
// wave: A-through-LDS prologue (3 barriers), per-chunk B staging (2 ds_write
// + 8 ds_read_b128 + 2 barriers). All deleted:
//  * Af: direct from global (R14/R15 harness-verified pattern).
//  * Bf: direct from global/L2 in the mt loop — per read, lanes 0-31 and
//    32-63 each cover a contiguous 512B segment (perfect coalescing); 32
//    waves/CU of independent loads hide the ~200cyc L2 latency.
//  * LDS = scr (8KB) only; barriers 7 -> 4 per block.
// min1 DPP epilogue + scr/combine dance: R17-verbatim (absmax 0.0).
__global__ __launch_bounds__(256) void chamfer_mfma(
        const s16x8* __restrict__ Afrag, const s16x8* __restrict__ Bfrag,
        unsigned int* __restrict__ min1, unsigned int* __restrict__ min2) {
    __shared__ float scr[4][8][2][32];   // wave x tile x half x col = 8KB

    const int bid = blockIdx.x;
    const int b   = bid >> 10;           // 1024 blocks per batch
    const int rr  = bid & 1023;
    const int ob  = rr >> 4;             // 64 owner blocks (256 rows each)
    const int bin = rr & 15;             // 16 scan bins of 512
    const int nb    = ob * 256;
    const int mbase = bin * (CH * 256);

    const int t = threadIdx.x;
    const int w = t >> 6, l = t & 63;
    const int lc = l & 31, lh = l >> 5;

    const s16x8* Ab = Afrag + (size_t)(b * 2) * N_;
    const s16x8* Bb = Bfrag + (size_t)(b * 2) * M_;
    unsigned int* m1g = min1 + (size_t)b * N_;
    unsigned int* m2g = min2 + (size_t)b * M_;

    // Af direct from global (R14/R15 harness-verified)
    s16x8 Af0 = Ab[(size_t)lh * N_ + nb + w * 64 + lc];
    s16x8 Af1 = Ab[(size_t)lh * N_ + nb + w * 64 + 32 + lc];

    f32x16 mn1a, mn1b;
    #pragma unroll
    for (int i = 0; i < 16; i++) { mn1a[i] = 3.402823466e38f; mn1b[i] = 3.402823466e38f; }
    f32x16 zacc;
    #pragma unroll
    for (int i = 0; i < 16; i++) zacc[i] = 0.f;

    const s16x8* Bq = Bb + (size_t)lh * M_;   // this lane's k-half plane

    // ---- chunk loop (B direct from L2; no staging, no prefetch regs) ----
    for (int c = 0; c < CH; c++) {
        #pragma unroll 2
        for (int mt = 0; mt < 8; mt++) {
            s16x8 Bf = Bq[mbase + c * 256 + mt * 32 + lc];
            f32x16 aA = __builtin_amdgcn_mfma_f32_32x32x16_bf16(Af0, Bf, zacc, 0, 0, 0);
            f32x16 aB = __builtin_amdgcn_mfma_f32_32x32x16_bf16(Af1, Bf, zacc, 0, 0, 0);
            #pragma unroll
            for (int i = 0; i < 16; i++) {
                mn1a[i] = fminf(mn1a[i], aA[i]);
                mn1b[i] = fminf(mn1b[i], aB[i]);
            }
            float f0 = min3f(aA[0], aA[1], aA[2]);
            float f1 = min3f(aA[3], aA[4], aA[5]);
            float f2 = min3f(aA[6], aA[7], aA[8]);
            float f3 = min3f(aA[9], aA[10], aA[11]);
            float f4 = min3f(aA[12], aA[13], aA[14]);
            float f5 = min3f(aA[15], aB[0], aB[1]);
            float f6 = min3f(aB[2], aB[3], aB[4]);
            float f7 = min3f(aB[5], aB[6], aB[7]);
            float f8 = min3f(aB[8], aB[9], aB[10]);
            float f9 = min3f(aB[11], aB[12], aB[13]);
            float g0 = min3f(f0, f1, f2);
            float g1 = min3f(f3, f4, f5);
            float g2 = min3f(f6, f7, f8);
            float g3 = min3f(f9, aB[14], aB[15]);
            float m2 = fminf(fminf(g0, g1), fminf(g2, g3));
            scr[w][mt][lh][lc] = m2;     // both halves, unmerged (no shfl)
        }
        __syncthreads();   // scr complete
        {
            int mt2 = t >> 5, cc = t & 31;
            float v = fminf(
                fminf(fminf(scr[0][mt2][0][cc], scr[0][mt2][1][cc]),
                      fminf(scr[1][mt2][0][cc], scr[1][mt2][1][cc])),
                fminf(fminf(scr[2][mt2][0][cc], scr[2][mt2][1][cc]),
                      fminf(scr[3][mt2][0][cc], scr[3][mt2][1][cc])));
            atomicMin(&m2g[mbase + c * 256 + mt2 * 32 + cc], __float_as_uint(v));
        }
        __syncthreads();   // scr reads done before next chunk overwrites
    }

    // ---- epilogue: min1 via DPP (VALU) — zero DS-pipe traffic ----
    #pragma unroll
    for (int i = 0; i < 16; i++) {
        float v = redmin32_dpp(mn1a[i]);   // valid at lanes 31 / 63
        float u = redmin32_dpp(mn1b[i]);
        if (lc == 31) {
            int row = nb + w * 64 + (i & 3) + 8 * (i >> 2) + 4 * lh;
            atomicMin(&m1g[row], __float_as_uint(v));
            atomicMin(&m1g[row + 32], __float_as_uint(u));
        }
    }
}

// ROUND-16-verbatim wide finalize (48 blocks; ticket combine proven).
__global__ __launch_bounds__(256) void finalize_wide(
        const float* __restrict__ wts,
        const unsigned int* __restrict__ min1,
        const unsigned int* __restrict__ min2,
        const float* __restrict__ wmax_part,
        unsigned int* __restrict__ ctr,
        float* __restrict__ out) {
    __shared__ float red[4];
    __shared__ unsigned tk_sh;
    unsigned int* cntF = ctr + 160;
    float* acc = (float*)(ctr + 168);    // 6 floats, zeroed by init_ws

    const int blk = blockIdx.x;
    const int t = threadIdx.x;

    if (blk < 32) {
        int b = blk >> 4, sl = blk & 15;
        float lm = wmax_part[b * 256 + t];
        float gmax = blk_reduce_max(lm, red);
        int base = b * N_ + sl * 1024;
        float se = 0.f, swm = 0.f;
        #pragma unroll
        for (int i = 0; i < 4; i++) {
            int idx = base + i * 256 + t;
            float e = expf(wts[idx] - gmax);
            se += e;
            swm += e * __uint_as_float(min1[idx]);
        }
        float tse = blk_reduce_sum(se, red);
        float tswm = blk_reduce_sum(swm, red);
        if (t == 0) {
            atomicAdd(&acc[b * 3 + 0], tse);
            atomicAdd(&acc[b * 3 + 1], tswm);
        }
    } else {
        int k = blk - 32;
        int b = k >> 3, sl = k & 7;
        int base = b * M_ + sl * 1024;
        float s = 0.f;
        #pragma unroll
        for (int i = 0; i < 4; i++)
            s += __uint_as_float(min2[base + i * 256 + t]);
        float ts = blk_reduce_sum(s, red);
        if (t == 0) atomicAdd(&acc[b * 3 + 2], ts);
    }

    // last-ticket combine (release = vmcnt(0): this wave's acc adds complete)
    asm volatile("s_waitcnt vmcnt(0)" ::: "memory");
    __syncthreads();
    if (t == 0) tk_sh = atomicAdd(cntF, 1u);
    __syncthreads();
    if (tk_sh == 47u && t == 0) {
        float s0 = atomicAdd(&acc[0], 0.0f);   // coherent RMW reads
        float s1 = atomicAdd(&acc[1], 0.0f);
        float s2 = atomicAdd(&acc[2], 0.0f);
        float s3 = atomicAdd(&acc[3], 0.0f);
        float s4 = atomicAdd(&acc[4], 0.0f);
        float s5 = atomicAdd(&acc[5], 0.0f);
        out[0] = ((s1 / s0 + s2 * (1.0f / (float)M_)) +
                  (s4 / s3 + s5 * (1.0f / (float)M_))) * (1.0f / (float)B_);
    }
}

// ---------------- launch ----------------

extern "C" void kernel_launch(void* const* d_in, const int* in_sizes, int n_in,
                              void* d_out, int out_size, void* d_ws, size_t ws_size,
                              hipStream_t stream) {
    const float* p1  = (const float*)d_in[0];  // (B, N, 3)
    const float* p2  = (const float*)d_in[1];  // (B, M, 3)
    const float* wts = (const float*)d_in[2];  // (B, N)
    float* out = (float*)d_out;

    // ws: min1 (128KB) | min2 (64KB) | wmax 512f | ctr 256u32 (pad to 4KB) |
    //     Afrag B*2*N quads (1MB) | Bfrag B*2*M quads (0.5MB)
    unsigned int* min1 = (unsigned int*)d_ws;            // B*N
    unsigned int* min2 = min1 + B_ * N_;                 // B*M
    float* wmax_part = (float*)(min2 + B_ * M_);         // 512 floats
    unsigned int* ctr = (unsigned int*)(wmax_part + 512);// 256 u32
    char* frag_base = (char*)d_ws + 196608 + 4096;       // 16B aligned
    s16x8* Afrag = (s16x8*)frag_base;                    // B*2*N quads
    s16x8* Bfrag = Afrag + B_ * 2 * N_;                  // B*2*M quads

    // 192 blocks = (B*N + B*M) / 256
    init_ws<<<dim3((B_ * N_ + B_ * M_) / 256), dim3(256), 0, stream>>>(
        wts, p1, p2, min1, min2, wmax_part, ctr, Afrag, Bfrag, out);
    // 2 batches * 64 owner-blocks * 16 scan-bins = 2048 blocks
    chamfer_mfma<<<dim3(B_ * (N_ / 256) * (M_ / (CH * 256))), dim3(256), 0, stream>>>(
        Afrag, Bfrag, min1, min2);
    finalize_wide<<<dim3(48), dim3(256), 0, stream>>>(
        wts, min1, min2, wmax_part, ctr, out);
}

// Round 19
// 40.860 us; speedup vs baseline: 1.2136x; 1.2136x over previous
//
#include <hip/hip_runtime.h>

#define B_ 2
#define N_ 16384
#define M_ 8192
#define CH 2                      // scan chunks per block (2*256 = 512 cols)

typedef float f32x4 __attribute__((ext_vector_type(4)));
typedef float f32x16 __attribute__((ext_vector_type(16)));
typedef short s16x8 __attribute__((ext_vector_type(8)));

__device__ inline float min3f(float a, float b, float c) {
    float d;
    asm("v_min3_f32 %0, %1, %2, %3" : "=v"(d) : "v"(a), "v"(b), "v"(c));
    return d;
}

// ---- DPP 32-lane min reduction (VALU pipe — no DS/shuffle traffic) ----
// R17-verified (absmax 0.0). Valid at lanes 31 and 63 after shr1/2/4/8+bcast15.
__device__ inline float dpp_min_step(float v, const int ctrl) {
    int vi = __float_as_int(v);
    int s;
    switch (ctrl) {   // builtin requires literal ctrl
        case 0x111: s = __builtin_amdgcn_update_dpp(vi, vi, 0x111, 0xf, 0xf, false); break;
        case 0x112: s = __builtin_amdgcn_update_dpp(vi, vi, 0x112, 0xf, 0xf, false); break;
        case 0x114: s = __builtin_amdgcn_update_dpp(vi, vi, 0x114, 0xf, 0xf, false); break;
        case 0x118: s = __builtin_amdgcn_update_dpp(vi, vi, 0x118, 0xf, 0xf, false); break;
        default:    s = __builtin_amdgcn_update_dpp(vi, vi, 0x142, 0xf, 0xf, false); break;
    }
    return fminf(v, __int_as_float(s));
}
__device__ inline float redmin32_dpp(float v) {
    v = dpp_min_step(v, 0x111);   // row_shr:1
    v = dpp_min_step(v, 0x112);   // row_shr:2
    v = dpp_min_step(v, 0x114);   // row_shr:4
    v = dpp_min_step(v, 0x118);   // row_shr:8
    v = dpp_min_step(v, 0x142);   // row_bcast:15
    return v;                     // valid at lanes 31 and 63
}

// RNE f32 -> bf16 (bits)
__device__ inline unsigned short f2bf(float f) {
    unsigned int u = __float_as_uint(f);
    u += 0x7FFFu + ((u >> 16) & 1u);
    return (unsigned short)(u >> 16);
}
__device__ inline float bf2f(unsigned short h) {
    return __uint_as_float(((unsigned int)h) << 16);
}
// 2-way bf16 split: v ~= h + m, residual ~2^-18 rel
__device__ inline void split2(float v, unsigned short& hb, unsigned short& mb) {
    hb = f2bf(v);
    mb = f2bf(v - bf2f(hb));
}

#define ONE_BF ((short)0x3F80)

// K=16 slot maps — verbatim from the ROUND-12/16/17 VERIFIED kernels
__device__ inline void buildA2(float x0, float x1, float x2,
                               s16x8& q0, s16x8& q1) {
    float sq = fmaf(x0, x0, fmaf(x1, x1, x2 * x2));
    unsigned short uh[3], um[3], sh, sm;
    split2(-2.f * x0, uh[0], um[0]);
    split2(-2.f * x1, uh[1], um[1]);
    split2(-2.f * x2, uh[2], um[2]);
    split2(sq, sh, sm);
    q0 = (s16x8){(short)uh[0], (short)uh[1], (short)uh[2], (short)uh[0],
                 (short)uh[1], (short)uh[2], (short)um[0], (short)um[1]};
    q1 = (s16x8){(short)um[2], (short)um[0], (short)um[1], (short)um[2],
                 (short)sh, (short)sm, ONE_BF, ONE_BF};
}
__device__ inline void buildB2(float y0, float y1, float y2,
                               s16x8& q0, s16x8& q1) {
    float sq = fmaf(y0, y0, fmaf(y1, y1, y2 * y2));
    unsigned short yh[3], ym[3], sh, sm;
    split2(y0, yh[0], ym[0]);
    split2(y1, yh[1], ym[1]);
    split2(y2, yh[2], ym[2]);
    split2(sq, sh, sm);
    q0 = (s16x8){(short)yh[0], (short)yh[1], (short)yh[2], (short)ym[0],
                 (short)ym[1], (short)ym[2], (short)yh[0], (short)yh[1]};
    q1 = (s16x8){(short)yh[2], (short)ym[0], (short)ym[1], (short)ym[2],
                 ONE_BF, ONE_BF, (short)sh, (short)sm};
}

// ---------------- block reductions (4 waves, shared scratch passed in) -------

__device__ inline float blk_reduce_max(float v, float* red) {
    #pragma unroll
    for (int off = 32; off; off >>= 1) v = fmaxf(v, __shfl_xor(v, off));
    int wid = threadIdx.x >> 6;
    int lane = threadIdx.x & 63;
    if (lane == 0) red[wid] = v;
    __syncthreads();
    if (wid == 0) {
        v = (lane < 4) ? red[lane] : -3.402823466e38f;
        #pragma unroll
        for (int off = 32; off; off >>= 1) v = fmaxf(v, __shfl_xor(v, off));
        if (lane == 0) red[0] = v;
    }
    __syncthreads();
    v = red[0];
    __syncthreads();
    return v;
}

__device__ inline float blk_reduce_sum(float v, float* red) {
    #pragma unroll
    for (int off = 32; off; off >>= 1) v += __shfl_xor(v, off);
    int wid = threadIdx.x >> 6;
    int lane = threadIdx.x & 63;
    if (lane == 0) red[wid] = v;
    __syncthreads();
    if (wid == 0) {
        v = (lane < 4) ? red[lane] : 0.0f;
        #pragma unroll
        for (int off = 32; off; off >>= 1) v += __shfl_xor(v, off);
        if (lane == 0) red[0] = v;
    }
    __syncthreads();
    v = red[0];
    __syncthreads();
    return v;
}

// ---------------- kernels ----------------

// grid 192 blocks — R12/R16/R17-verbatim init + ctr/acc zeroing.
__global__ __launch_bounds__(256) void init_ws(const float* __restrict__ wts,
                                               const float* __restrict__ p1,
                                               const float* __restrict__ p2,
                                               unsigned int* min1, unsigned int* min2,
                                               float* __restrict__ wmax_part,
                                               unsigned int* __restrict__ ctr,
                                               s16x8* __restrict__ Afrag,
                                               s16x8* __restrict__ Bfrag,
                                               float* out) {
    int j = blockIdx.x * 256 + threadIdx.x;   // [0, B*N + B*M)
    if (j < 256) ctr[j] = 0u;                 // cntF @160, acc @168
    if (j == 0) out[0] = 0.0f;
    if (j < B_ * N_) {
        min1[j] = 0x7F7FFFFFu;                // FLT_MAX bits
        float v = wts[j];
        #pragma unroll
        for (int off = 32; off; off >>= 1) v = fmaxf(v, __shfl_xor(v, off));
        if ((j & 63) == 0) wmax_part[j >> 6] = v;   // 512 wave partials

        int b = j >> 14, n = j & (N_ - 1);
        const float* px = p1 + (size_t)j * 3;
        s16x8 q0, q1;
        buildA2(px[0], px[1], px[2], q0, q1);
        Afrag[((size_t)b * 2 + 0) * N_ + n] = q0;
        Afrag[((size_t)b * 2 + 1) * N_ + n] = q1;
    } else {
        int k = j - B_ * N_;                  // [0, B*M)
        min2[k] = 0x7F7FFFFFu;
        int b = k >> 13, m = k & (M_ - 1);
        const float* py = p2 + (size_t)k * 3;
        s16x8 q0, q1;
        buildB2(py[0], py[1], py[2], q0, q1);
        Bfrag[((size_t)b * 2 + 0) * M_ + m] = q0;
        Bfrag[((size_t)b * 2 + 1) * M_ + m] = q1;
    }
}

// ROUND-19: R17's verified chamfer (43.2us total, best) with the inner loop
// EMPTIED OF ALL SYNCHRONIZATION. R18 proved LDS staging must stay (direct
// L2 reads regressed 6.4us: dependent load->MFMA latency exposed). R17's
// remaining in-loop structure: 4 barriers + 2 combine/atomic phases (they
// synchronized Bsh restaging AND scr). Both reasons removed:
//  (1) Bsh[4][256] (16KB) holds BOTH chunks, staged once in the prologue ->
//      no restaging, no restage barriers.
//  (2) scr[4][16][2][32] (16KB) holds all 16 (c,mt) wave-partials; in-loop
//      min2 is just the per-wave scr write (own slice, no sync). Combine =
//      epilogue: 1 barrier + 2 cols/thread (8 reads + 1 atomicMin each).
// Inner loop = flat 16x {1 ds_read_b128, 2 MFMA, fold, 1 ds_write} — zero
// barriers, zero atomics. Barriers/block 7 -> 4. A staged through scr
// (R17's proven pattern); B loads issued first (fly under A staging).
// Fold ops, scr values, atomics, DPP epilogue bit-identical -> absmax 0.0.
__global__ __launch_bounds__(256) void chamfer_mfma(
        const s16x8* __restrict__ Afrag, const s16x8* __restrict__ Bfrag,
        unsigned int* __restrict__ min1, unsigned int* __restrict__ min2) {
    __shared__ s16x8 Bsh[4][256];        // [chunk*2+khalf][col] = 16KB
    __shared__ float scr[4][16][2][32];  // wave x (c*8+mt) x half x col = 16KB

    const int bid = blockIdx.x;
    const int b   = bid >> 10;           // 1024 blocks per batch
    const int rr  = bid & 1023;
    const int ob  = rr >> 4;             // 64 owner blocks (256 rows each)
    const int bin = rr & 15;             // 16 scan bins of 512
    const int nb    = ob * 256;
    const int mbase = bin * (CH * 256);

    const int t = threadIdx.x;
    const int w = t >> 6, l = t & 63;
    const int lc = l & 31, lh = l >> 5;

    const s16x8* Ab = Afrag + (size_t)(b * 2) * N_;
    const s16x8* Bb = Bfrag + (size_t)(b * 2) * M_;
    unsigned int* m1g = min1 + (size_t)b * N_;
    unsigned int* m2g = min2 + (size_t)b * M_;

    // ---- prologue: B loads (both chunks) issue first; A staged via scr ----
    s16x8 b0 = Bb[0 * M_ + mbase + t];          // c0, kh0
    s16x8 b1 = Bb[1 * M_ + mbase + t];          // c0, kh1
    s16x8 b2 = Bb[0 * M_ + mbase + 256 + t];    // c1, kh0
    s16x8 b3 = Bb[1 * M_ + mbase + 256 + t];    // c1, kh1
    {
        s16x8* As = (s16x8*)scr;                // 8KB of the 16KB scr
        As[0 * 256 + t] = Ab[0 * N_ + nb + t];
        As[1 * 256 + t] = Ab[1 * N_ + nb + t];
    }
    __syncthreads();
    s16x8 Af0, Af1;
    {
        const s16x8* As = (const s16x8*)scr;
        Af0 = As[lh * 256 + w * 64 + lc];        // row-tile r0 = nb + w*64
        Af1 = As[lh * 256 + w * 64 + 32 + lc];   // row-tile r1 = +32
    }
    __syncthreads();
    Bsh[0][t] = b0;
    Bsh[1][t] = b1;
    Bsh[2][t] = b2;
    Bsh[3][t] = b3;
    __syncthreads();

    f32x16 mn1a, mn1b;
    #pragma unroll
    for (int i = 0; i < 16; i++) { mn1a[i] = 3.402823466e38f; mn1b[i] = 3.402823466e38f; }
    f32x16 zacc;
    #pragma unroll
    for (int i = 0; i < 16; i++) zacc[i] = 0.f;

    // ---- flat inner loop: 16x {ds_read, 2 MFMA, fold, ds_write} — no sync --
    #pragma unroll 2
    for (int it = 0; it < CH * 8; it++) {
        const int c = it >> 3, mt = it & 7;
        s16x8 Bf = Bsh[c * 2 + lh][mt * 32 + lc];
        f32x16 aA = __builtin_amdgcn_mfma_f32_32x32x16_bf16(Af0, Bf, zacc, 0, 0, 0);
        f32x16 aB = __builtin_amdgcn_mfma_f32_32x32x16_bf16(Af1, Bf, zacc, 0, 0, 0);
        #pragma unroll
        for (int i = 0; i < 16; i++) {
            mn1a[i] = fminf(mn1a[i], aA[i]);
            mn1b[i] = fminf(mn1b[i], aB[i]);
        }
        float f0 = min3f(aA[0], aA[1], aA[2]);
        float f1 = min3f(aA[3], aA[4], aA[5]);
        float f2 = min3f(aA[6], aA[7], aA[8]);
        float f3 = min3f(aA[9], aA[10], aA[11]);
        float f4 = min3f(aA[12], aA[13], aA[14]);
        float f5 = min3f(aA[15], aB[0], aB[1]);
        float f6 = min3f(aB[2], aB[3], aB[4]);
        float f7 = min3f(aB[5], aB[6], aB[7]);
        float f8 = min3f(aB[8], aB[9], aB[10]);
        float f9 = min3f(aB[11], aB[12], aB[13]);
        float g0 = min3f(f0, f1, f2);
        float g1 = min3f(f3, f4, f5);
        float g2 = min3f(f6, f7, f8);
        float g3 = min3f(f9, aB[14], aB[15]);
        float m2 = fminf(fminf(g0, g1), fminf(g2, g3));
        scr[w][it][lh][lc] = m2;     // own slice; no synchronization needed
    }

    __syncthreads();   // all scr slots complete

    // ---- epilogue: min2 combine (2 cols/thread, 8 reads + 1 atomic each) ----
    #pragma unroll
    for (int rep = 0; rep < 2; rep++) {
        int cid = rep * 256 + t;             // [0, 512)
        int c = cid >> 8, rem = cid & 255;
        int slot = c * 8 + (rem >> 5), cc = rem & 31;
        float v = fminf(
            fminf(fminf(scr[0][slot][0][cc], scr[0][slot][1][cc]),
                  fminf(scr[1][slot][0][cc], scr[1][slot][1][cc])),
            fminf(fminf(scr[2][slot][0][cc], scr[2][slot][1][cc]),
                  fminf(scr[3][slot][0][cc], scr[3][slot][1][cc])));
        atomicMin(&m2g[mbase + cid], __float_as_uint(v));
    }

    // ---- epilogue: min1 via DPP (VALU) — zero DS-pipe traffic ----
    #pragma unroll
    for (int i = 0; i < 16; i++) {
        float v = redmin32_dpp(mn1a[i]);   // valid at lanes 31 / 63
        float u = redmin32_dpp(mn1b[i]);
        if (lc == 31) {
            int row = nb + w * 64 + (i & 3) + 8 * (i >> 2) + 4 * lh;
            atomicMin(&m1g[row], __float_as_uint(v));
            atomicMin(&m1g[row + 32], __float_as_uint(u));
        }
    }
}

// ROUND-16-verbatim wide finalize (48 blocks; ticket combine proven).
__global__ __launch_bounds__(256) void finalize_wide(
        const float* __restrict__ wts,
        const unsigned int* __restrict__ min1,
        const unsigned int* __restrict__ min2,
        const float* __restrict__ wmax_part,
        unsigned int* __restrict__ ctr,
        float* __restrict__ out) {
    __shared__ float red[4];
    __shared__ unsigned tk_sh;
    unsigned int* cntF = ctr + 160;
    float* acc = (float*)(ctr + 168);    // 6 floats, zeroed by init_ws

    const int blk = blockIdx.x;
    const int t = threadIdx.x;

    if (blk < 32) {
        int b = blk >> 4, sl = blk & 15;
        float lm = wmax_part[b * 256 + t];
        float gmax = blk_reduce_max(lm, red);
        int base = b * N_ + sl * 1024;
        float se = 0.f, swm = 0.f;
        #pragma unroll
        for (int i = 0; i < 4; i++) {
            int idx = base + i * 256 + t;
            float e = expf(wts[idx] - gmax);
            se += e;
            swm += e * __uint_as_float(min1[idx]);
        }
        float tse = blk_reduce_sum(se, red);
        float tswm = blk_reduce_sum(swm, red);
        if (t == 0) {
            atomicAdd(&acc[b * 3 + 0], tse);
            atomicAdd(&acc[b * 3 + 1], tswm);
        }
    } else {
        int k = blk - 32;
        int b = k >> 3, sl = k & 7;
        int base = b * M_ + sl * 1024;
        float s = 0.f;
        #pragma unroll
        for (int i = 0; i < 4; i++)
            s += __uint_as_float(min2[base + i * 256 + t]);
        float ts = blk_reduce_sum(s, red);
        if (t == 0) atomicAdd(&acc[b * 3 + 2], ts);
    }

    // last-ticket combine (release = vmcnt(0): this wave's acc adds complete)
    asm volatile("s_waitcnt vmcnt(0)" ::: "memory");
    __syncthreads();
    if (t == 0) tk_sh = atomicAdd(cntF, 1u);
    __syncthreads();
    if (tk_sh == 47u && t == 0) {
        float s0 = atomicAdd(&acc[0], 0.0f);   // coherent RMW reads
        float s1 = atomicAdd(&acc[1], 0.0f);
        float s2 = atomicAdd(&acc[2], 0.0f);
        float s3 = atomicAdd(&acc[3], 0.0f);
        float s4 = atomicAdd(&acc[4], 0.0f);
        float s5 = atomicAdd(&acc[5], 0.0f);
        out[0] = ((s1 / s0 + s2 * (1.0f / (float)M_)) +
                  (s4 / s3 + s5 * (1.0f / (float)M_))) * (1.0f / (float)B_);
    }
}

// ---------------- launch ----------------

extern "C" void kernel_launch(void* const* d_in, const int* in_sizes, int n_in,
                              void* d_out, int out_size, void* d_ws, size_t ws_size,
                              hipStream_t stream) {
    const float* p1  = (const float*)d_in[0];  // (B, N, 3)
    const float* p2  = (const float*)d_in[1];  // (B, M, 3)
    const float* wts = (const float*)d_in[2];  // (B, N)
    float* out = (float*)d_out;

    // ws: min1 (128KB) | min2 (64KB) | wmax 512f | ctr 256u32 (pad to 4KB) |
    //     Afrag B*2*N quads (1MB) | Bfrag B*2*M quads (0.5MB)
    unsigned int* min1 = (unsigned int*)d_ws;            // B*N
    unsigned int* min2 = min1 + B_ * N_;                 // B*M
    float* wmax_part = (float*)(min2 + B_ * M_);         // 512 floats
    unsigned int* ctr = (unsigned int*)(wmax_part + 512);// 256 u32
    char* frag_base = (char*)d_ws + 196608 + 4096;       // 16B aligned
    s16x8* Afrag = (s16x8*)frag_base;                    // B*2*N quads
    s16x8* Bfrag = Afrag + B_ * 2 * N_;                  // B*2*M quads

    // 192 blocks = (B*N + B*M) / 256
    init_ws<<<dim3((B_ * N_ + B_ * M_) / 256), dim3(256), 0, stream>>>(
        wts, p1, p2, min1, min2, wmax_part, ctr, Afrag, Bfrag, out);
    // 2 batches * 64 owner-blocks * 16 scan-bins = 2048 blocks
    chamfer_mfma<<<dim3(B_ * (N_ / 256) * (M_ / (CH * 256))), dim3(256), 0, stream>>>(
        Afrag, Bfrag, min1, min2);
    finalize_wide<<<dim3(48), dim3(256), 0, stream>>>(
        wts, min1, min2, wmax_part, ctr, out);
}

// Round 20
// 39.096 us; speedup vs baseline: 1.2684x; 1.0451x over previous
//
#include <hip/hip_runtime.h>

#define B_ 2
#define N_ 16384
#define M_ 8192
#define CH 4                      // scan chunks per block (4*256 = 1024 cols)

typedef float f32x4 __attribute__((ext_vector_type(4)));
typedef float f32x16 __attribute__((ext_vector_type(16)));
typedef short s16x8 __attribute__((ext_vector_type(8)));

__device__ inline float min3f(float a, float b, float c) {
    float d;
    asm("v_min3_f32 %0, %1, %2, %3" : "=v"(d) : "v"(a), "v"(b), "v"(c));
    return d;
}

// ---- DPP 32-lane min reduction (VALU pipe — no DS/shuffle traffic) ----
// R17/R19-verified (absmax 0.0). Valid at lanes 31/63 after shr1/2/4/8+bcast15.
__device__ inline float dpp_min_step(float v, const int ctrl) {
    int vi = __float_as_int(v);
    int s;
    switch (ctrl) {   // builtin requires literal ctrl
        case 0x111: s = __builtin_amdgcn_update_dpp(vi, vi, 0x111, 0xf, 0xf, false); break;
        case 0x112: s = __builtin_amdgcn_update_dpp(vi, vi, 0x112, 0xf, 0xf, false); break;
        case 0x114: s = __builtin_amdgcn_update_dpp(vi, vi, 0x114, 0xf, 0xf, false); break;
        case 0x118: s = __builtin_amdgcn_update_dpp(vi, vi, 0x118, 0xf, 0xf, false); break;
        default:    s = __builtin_amdgcn_update_dpp(vi, vi, 0x142, 0xf, 0xf, false); break;
    }
    return fminf(v, __int_as_float(s));
}
__device__ inline float redmin32_dpp(float v) {
    v = dpp_min_step(v, 0x111);   // row_shr:1
    v = dpp_min_step(v, 0x112);   // row_shr:2
    v = dpp_min_step(v, 0x114);   // row_shr:4
    v = dpp_min_step(v, 0x118);   // row_shr:8
    v = dpp_min_step(v, 0x142);   // row_bcast:15
    return v;                     // valid at lanes 31 and 63
}

// RNE f32 -> bf16 (bits)
__device__ inline unsigned short f2bf(float f) {
    unsigned int u = __float_as_uint(f);
    u += 0x7FFFu + ((u >> 16) & 1u);
    return (unsigned short)(u >> 16);
}
__device__ inline float bf2f(unsigned short h) {
    return __uint_as_float(((unsigned int)h) << 16);
}
// 2-way bf16 split: v ~= h + m, residual ~2^-18 rel
__device__ inline void split2(float v, unsigned short& hb, unsigned short& mb) {
    hb = f2bf(v);
    mb = f2bf(v - bf2f(hb));
}

#define ONE_BF ((short)0x3F80)

// K=16 slot maps — verbatim from the ROUND-12/16/17/19 VERIFIED kernels
__device__ inline void buildA2(float x0, float x1, float x2,
                               s16x8& q0, s16x8& q1) {
    float sq = fmaf(x0, x0, fmaf(x1, x1, x2 * x2));
    unsigned short uh[3], um[3], sh, sm;
    split2(-2.f * x0, uh[0], um[0]);
    split2(-2.f * x1, uh[1], um[1]);
    split2(-2.f * x2, uh[2], um[2]);
    split2(sq, sh, sm);
    q0 = (s16x8){(short)uh[0], (short)uh[1], (short)uh[2], (short)uh[0],
                 (short)uh[1], (short)uh[2], (short)um[0], (short)um[1]};
    q1 = (s16x8){(short)um[2], (short)um[0], (short)um[1], (short)um[2],
                 (short)sh, (short)sm, ONE_BF, ONE_BF};
}
__device__ inline void buildB2(float y0, float y1, float y2,
                               s16x8& q0, s16x8& q1) {
    float sq = fmaf(y0, y0, fmaf(y1, y1, y2 * y2));
    unsigned short yh[3], ym[3], sh, sm;
    split2(y0, yh[0], ym[0]);
    split2(y1, yh[1], ym[1]);
    split2(y2, yh[2], ym[2]);
    split2(sq, sh, sm);
    q0 = (s16x8){(short)yh[0], (short)yh[1], (short)yh[2], (short)ym[0],
                 (short)ym[1], (short)ym[2], (short)yh[0], (short)yh[1]};
    q1 = (s16x8){(short)yh[2], (short)ym[0], (short)ym[1], (short)ym[2],
                 ONE_BF, ONE_BF, (short)sh, (short)sm};
}

// ---------------- block reductions (4 waves, shared scratch passed in) -------

__device__ inline float blk_reduce_max(float v, float* red) {
    #pragma unroll
    for (int off = 32; off; off >>= 1) v = fmaxf(v, __shfl_xor(v, off));
    int wid = threadIdx.x >> 6;
    int lane = threadIdx.x & 63;
    if (lane == 0) red[wid] = v;
    __syncthreads();
    if (wid == 0) {
        v = (lane < 4) ? red[lane] : -3.402823466e38f;
        #pragma unroll
        for (int off = 32; off; off >>= 1) v = fmaxf(v, __shfl_xor(v, off));
        if (lane == 0) red[0] = v;
    }
    __syncthreads();
    v = red[0];
    __syncthreads();
    return v;
}

__device__ inline float blk_reduce_sum(float v, float* red) {
    #pragma unroll
    for (int off = 32; off; off >>= 1) v += __shfl_xor(v, off);
    int wid = threadIdx.x >> 6;
    int lane = threadIdx.x & 63;
    if (lane == 0) red[wid] = v;
    __syncthreads();
    if (wid == 0) {
        v = (lane < 4) ? red[lane] : 0.0f;
        #pragma unroll
        for (int off = 32; off; off >>= 1) v += __shfl_xor(v, off);
        if (lane == 0) red[0] = v;
    }
    __syncthreads();
    v = red[0];
    __syncthreads();
    return v;
}

// ---------------- kernels ----------------

// grid 192 blocks — R12/R16/R17/R19-verbatim init + ctr/acc zeroing.
__global__ __launch_bounds__(256) void init_ws(const float* __restrict__ wts,
                                               const float* __restrict__ p1,
                                               const float* __restrict__ p2,
                                               unsigned int* min1, unsigned int* min2,
                                               float* __restrict__ wmax_part,
                                               unsigned int* __restrict__ ctr,
                                               s16x8* __restrict__ Afrag,
                                               s16x8* __restrict__ Bfrag,
                                               float* out) {
    int j = blockIdx.x * 256 + threadIdx.x;   // [0, B*N + B*M)
    if (j < 256) ctr[j] = 0u;                 // cntF @160, acc @168
    if (j == 0) out[0] = 0.0f;
    if (j < B_ * N_) {
        min1[j] = 0x7F7FFFFFu;                // FLT_MAX bits
        float v = wts[j];
        #pragma unroll
        for (int off = 32; off; off >>= 1) v = fmaxf(v, __shfl_xor(v, off));
        if ((j & 63) == 0) wmax_part[j >> 6] = v;   // 512 wave partials

        int b = j >> 14, n = j & (N_ - 1);
        const float* px = p1 + (size_t)j * 3;
        s16x8 q0, q1;
        buildA2(px[0], px[1], px[2], q0, q1);
        Afrag[((size_t)b * 2 + 0) * N_ + n] = q0;
        Afrag[((size_t)b * 2 + 1) * N_ + n] = q1;
    } else {
        int k = j - B_ * N_;                  // [0, B*M)
        min2[k] = 0x7F7FFFFFu;
        int b = k >> 13, m = k & (M_ - 1);
        const float* py = p2 + (size_t)k * 3;
        s16x8 q0, q1;
        buildB2(py[0], py[1], py[2], q0, q1);
        Bfrag[((size_t)b * 2 + 0) * M_ + m] = q0;
        Bfrag[((size_t)b * 2 + 1) * M_ + m] = q1;
    }
}

// ROUND-20: R19's verified kernel (40.9us, best) with CH=2 -> 4 via TWO
// half-loops sharing ONE prologue/epilogue. Rationale: R19's per-block fixed
// cost (A-stage + 3 prologue barriers + Af LDS round-trip + 320-cyc DPP min1
// epilogue + min1 atomics) is paid by all 2048 blocks but independent of
// scan width — doubling scan per block halves it per unit work WITHOUT
// touching the verified inner loop (R7 lesson: lowest-risk amortization).
// Grid 1024 (4 blocks/CU, one generation). All 8 B-chunk loads issue in the
// prologue (in flight under A staging / h0 loop); between halves: {barrier,
// min2-combine(c0,c1), restage Bsh<-(c2,c3), barrier}. mn1 accumulates
// across all 32 iterations -> single shared DPP epilogue (bit-identical
// fold math -> absmax 0.0 expected).
__global__ __launch_bounds__(256) void chamfer_mfma(
        const s16x8* __restrict__ Afrag, const s16x8* __restrict__ Bfrag,
        unsigned int* __restrict__ min1, unsigned int* __restrict__ min2) {
    __shared__ s16x8 Bsh[4][256];        // [chunkpair*2+khalf][col] = 16KB
    __shared__ float scr[4][16][2][32];  // wave x (c*8+mt) x half x col = 16KB

    const int bid = blockIdx.x;
    const int b   = bid >> 9;            // 512 blocks per batch
    const int rr  = bid & 511;
    const int ob  = rr >> 3;             // 64 owner blocks (256 rows each)
    const int bin = rr & 7;              // 8 scan bins of 1024
    const int nb    = ob * 256;
    const int mbase = bin * (CH * 256);

    const int t = threadIdx.x;
    const int w = t >> 6, l = t & 63;
    const int lc = l & 31, lh = l >> 5;

    const s16x8* Ab = Afrag + (size_t)(b * 2) * N_;
    const s16x8* Bb = Bfrag + (size_t)(b * 2) * M_;
    unsigned int* m1g = min1 + (size_t)b * N_;
    unsigned int* m2g = min2 + (size_t)b * M_;

    // ---- prologue: ALL B loads (4 chunks) issue first; A staged via scr ----
    s16x8 b0 = Bb[0 * M_ + mbase + t];          // c0, kh0
    s16x8 b1 = Bb[1 * M_ + mbase + t];          // c0, kh1
    s16x8 b2 = Bb[0 * M_ + mbase + 256 + t];    // c1, kh0
    s16x8 b3 = Bb[1 * M_ + mbase + 256 + t];    // c1, kh1
    s16x8 b4 = Bb[0 * M_ + mbase + 512 + t];    // c2, kh0
    s16x8 b5 = Bb[1 * M_ + mbase + 512 + t];    // c2, kh1
    s16x8 b6 = Bb[0 * M_ + mbase + 768 + t];    // c3, kh0
    s16x8 b7 = Bb[1 * M_ + mbase + 768 + t];    // c3, kh1
    {
        s16x8* As = (s16x8*)scr;                // 8KB of the 16KB scr
        As[0 * 256 + t] = Ab[0 * N_ + nb + t];
        As[1 * 256 + t] = Ab[1 * N_ + nb + t];
    }
    __syncthreads();
    s16x8 Af0, Af1;
    {
        const s16x8* As = (const s16x8*)scr;
        Af0 = As[lh * 256 + w * 64 + lc];        // row-tile r0 = nb + w*64
        Af1 = As[lh * 256 + w * 64 + 32 + lc];   // row-tile r1 = +32
    }
    __syncthreads();
    Bsh[0][t] = b0;
    Bsh[1][t] = b1;
    Bsh[2][t] = b2;
    Bsh[3][t] = b3;
    __syncthreads();

    f32x16 mn1a, mn1b;
    #pragma unroll
    for (int i = 0; i < 16; i++) { mn1a[i] = 3.402823466e38f; mn1b[i] = 3.402823466e38f; }
    f32x16 zacc;
    #pragma unroll
    for (int i = 0; i < 16; i++) zacc[i] = 0.f;

    // ---- two half-loops; each is R19's verbatim sync-free 16-iter body ----
    #pragma unroll 1
    for (int h = 0; h < 2; h++) {
        #pragma unroll 2
        for (int it = 0; it < 16; it++) {
            const int c = it >> 3, mt = it & 7;
            s16x8 Bf = Bsh[c * 2 + lh][mt * 32 + lc];
            f32x16 aA = __builtin_amdgcn_mfma_f32_32x32x16_bf16(Af0, Bf, zacc, 0, 0, 0);
            f32x16 aB = __builtin_amdgcn_mfma_f32_32x32x16_bf16(Af1, Bf, zacc, 0, 0, 0);
            #pragma unroll
            for (int i = 0; i < 16; i++) {
                mn1a[i] = fminf(mn1a[i], aA[i]);
                mn1b[i] = fminf(mn1b[i], aB[i]);
            }
            float f0 = min3f(aA[0], aA[1], aA[2]);
            float f1 = min3f(aA[3], aA[4], aA[5]);
            float f2 = min3f(aA[6], aA[7], aA[8]);
            float f3 = min3f(aA[9], aA[10], aA[11]);
            float f4 = min3f(aA[12], aA[13], aA[14]);
            float f5 = min3f(aA[15], aB[0], aB[1]);
            float f6 = min3f(aB[2], aB[3], aB[4]);
            float f7 = min3f(aB[5], aB[6], aB[7]);
            float f8 = min3f(aB[8], aB[9], aB[10]);
            float f9 = min3f(aB[11], aB[12], aB[13]);
            float g0 = min3f(f0, f1, f2);
            float g1 = min3f(f3, f4, f5);
            float g2 = min3f(f6, f7, f8);
            float g3 = min3f(f9, aB[14], aB[15]);
            float m2 = fminf(fminf(g0, g1), fminf(g2, g3));
            scr[w][it][lh][lc] = m2;     // own slice; no synchronization
        }

        __syncthreads();   // scr half complete; all waves done reading Bsh

        // min2 combine for this half's 2 chunks (2 cols/thread)
        #pragma unroll
        for (int rep = 0; rep < 2; rep++) {
            int cid = rep * 256 + t;             // [0, 512)
            int c = cid >> 8, rem = cid & 255;
            int slot = c * 8 + (rem >> 5), cc = rem & 31;
            float v = fminf(
                fminf(fminf(scr[0][slot][0][cc], scr[0][slot][1][cc]),
                      fminf(scr[1][slot][0][cc], scr[1][slot][1][cc])),
                fminf(fminf(scr[2][slot][0][cc], scr[2][slot][1][cc]),
                      fminf(scr[3][slot][0][cc], scr[3][slot][1][cc])));
            atomicMin(&m2g[mbase + h * 512 + cid], __float_as_uint(v));
        }

        if (h == 0) {
            // restage Bsh with chunks 2,3 (loaded in prologue, long in flight)
            Bsh[0][t] = b4;
            Bsh[1][t] = b5;
            Bsh[2][t] = b6;
            Bsh[3][t] = b7;
            __syncthreads();   // combine reads done + Bsh c2/c3 visible
        }
    }

    // ---- epilogue: min1 via DPP (VALU) — shared across both halves ----
    #pragma unroll
    for (int i = 0; i < 16; i++) {
        float v = redmin32_dpp(mn1a[i]);   // valid at lanes 31 / 63
        float u = redmin32_dpp(mn1b[i]);
        if (lc == 31) {
            int row = nb + w * 64 + (i & 3) + 8 * (i >> 2) + 4 * lh;
            atomicMin(&m1g[row], __float_as_uint(v));
            atomicMin(&m1g[row + 32], __float_as_uint(u));
        }
    }
}

// ROUND-16-verbatim wide finalize (48 blocks; ticket combine proven).
__global__ __launch_bounds__(256) void finalize_wide(
        const float* __restrict__ wts,
        const unsigned int* __restrict__ min1,
        const unsigned int* __restrict__ min2,
        const float* __restrict__ wmax_part,
        unsigned int* __restrict__ ctr,
        float* __restrict__ out) {
    __shared__ float red[4];
    __shared__ unsigned tk_sh;
    unsigned int* cntF = ctr + 160;
    float* acc = (float*)(ctr + 168);    // 6 floats, zeroed by init_ws

    const int blk = blockIdx.x;
    const int t = threadIdx.x;

    if (blk < 32) {
        int b = blk >> 4, sl = blk & 15;
        float lm = wmax_part[b * 256 + t];
        float gmax = blk_reduce_max(lm, red);
        int base = b * N_ + sl * 1024;
        float se = 0.f, swm = 0.f;
        #pragma unroll
        for (int i = 0; i < 4; i++) {
            int idx = base + i * 256 + t;
            float e = expf(wts[idx] - gmax);
            se += e;
            swm += e * __uint_as_float(min1[idx]);
        }
        float tse = blk_reduce_sum(se, red);
        float tswm = blk_reduce_sum(swm, red);
        if (t == 0) {
            atomicAdd(&acc[b * 3 + 0], tse);
            atomicAdd(&acc[b * 3 + 1], tswm);
        }
    } else {
        int k = blk - 32;
        int b = k >> 3, sl = k & 7;
        int base = b * M_ + sl * 1024;
        float s = 0.f;
        #pragma unroll
        for (int i = 0; i < 4; i++)
            s += __uint_as_float(min2[base + i * 256 + t]);
        float ts = blk_reduce_sum(s, red);
        if (t == 0) atomicAdd(&acc[b * 3 + 2], ts);
    }

    // last-ticket combine (release = vmcnt(0): this wave's acc adds complete)
    asm volatile("s_waitcnt vmcnt(0)" ::: "memory");
    __syncthreads();
    if (t == 0) tk_sh = atomicAdd(cntF, 1u);
    __syncthreads();
    if (tk_sh == 47u && t == 0) {
        float s0 = atomicAdd(&acc[0], 0.0f);   // coherent RMW reads
        float s1 = atomicAdd(&acc[1], 0.0f);
        float s2 = atomicAdd(&acc[2], 0.0f);
        float s3 = atomicAdd(&acc[3], 0.0f);
        float s4 = atomicAdd(&acc[4], 0.0f);
        float s5 = atomicAdd(&acc[5], 0.0f);
        out[0] = ((s1 / s0 + s2 * (1.0f / (float)M_)) +
                  (s4 / s3 + s5 * (1.0f / (float)M_))) * (1.0f / (float)B_);
    }
}

// ---------------- launch ----------------

extern "C" void kernel_launch(void* const* d_in, const int* in_sizes, int n_in,
                              void* d_out, int out_size, void* d_ws, size_t ws_size,
                              hipStream_t stream) {
    const float* p1  = (const float*)d_in[0];  // (B, N, 3)
    const float* p2  = (const float*)d_in[1];  // (B, M, 3)
    const float* wts = (const float*)d_in[2];  // (B, N)
    float* out = (float*)d_out;

    // ws: min1 (128KB) | min2 (64KB) | wmax 512f | ctr 256u32 (pad to 4KB) |
    //     Afrag B*2*N quads (1MB) | Bfrag B*2*M quads (0.5MB)
    unsigned int* min1 = (unsigned int*)d_ws;            // B*N
    unsigned int* min2 = min1 + B_ * N_;                 // B*M
    float* wmax_part = (float*)(min2 + B_ * M_);         // 512 floats
    unsigned int* ctr = (unsigned int*)(wmax_part + 512);// 256 u32
    char* frag_base = (char*)d_ws + 196608 + 4096;       // 16B aligned
    s16x8* Afrag = (s16x8*)frag_base;                    // B*2*N quads
    s16x8* Bfrag = Afrag + B_ * 2 * N_;                  // B*2*M quads

    // 192 blocks = (B*N + B*M) / 256
    init_ws<<<dim3((B_ * N_ + B_ * M_) / 256), dim3(256), 0, stream>>>(
        wts, p1, p2, min1, min2, wmax_part, ctr, Afrag, Bfrag, out);
    // 2 batches * 64 owner-blocks * 8 scan-bins = 1024 blocks (4/CU)
    chamfer_mfma<<<dim3(B_ * (N_ / 256) * (M_ / (CH * 256))), dim3(256), 0, stream>>>(
        Afrag, Bfrag, min1, min2);
    finalize_wide<<<dim3(48), dim3(256), 0, stream>>>(
        wts, min1, min2, wmax_part, ctr, out);
}

// Round 22
// 38.426 us; speedup vs baseline: 1.2905x; 1.0174x over previous
//
#include <hip/hip_runtime.h>

#define B_ 2
#define N_ 16384
#define M_ 8192
#define CH 8                      // scan chunks per block (8*256 = 2048 cols)

typedef float f32x4 __attribute__((ext_vector_type(4)));
typedef float f32x16 __attribute__((ext_vector_type(16)));
typedef short s16x8 __attribute__((ext_vector_type(8)));

__device__ inline float min3f(float a, float b, float c) {
    float d;
    asm("v_min3_f32 %0, %1, %2, %3" : "=v"(d) : "v"(a), "v"(b), "v"(c));
    return d;
}

// ---- DPP 32-lane min reduction (VALU pipe — no DS/shuffle traffic) ----
// R17/R19/R20-verified (absmax 0.0). Valid at lanes 31/63 after shr+bcast.
__device__ inline float dpp_min_step(float v, const int ctrl) {
    int vi = __float_as_int(v);
    int s;
    switch (ctrl) {   // builtin requires literal ctrl
        case 0x111: s = __builtin_amdgcn_update_dpp(vi, vi, 0x111, 0xf, 0xf, false); break;
        case 0x112: s = __builtin_amdgcn_update_dpp(vi, vi, 0x112, 0xf, 0xf, false); break;
        case 0x114: s = __builtin_amdgcn_update_dpp(vi, vi, 0x114, 0xf, 0xf, false); break;
        case 0x118: s = __builtin_amdgcn_update_dpp(vi, vi, 0x118, 0xf, 0xf, false); break;
        default:    s = __builtin_amdgcn_update_dpp(vi, vi, 0x142, 0xf, 0xf, false); break;
    }
    return fminf(v, __int_as_float(s));
}
__device__ inline float redmin32_dpp(float v) {
    v = dpp_min_step(v, 0x111);   // row_shr:1
    v = dpp_min_step(v, 0x112);   // row_shr:2
    v = dpp_min_step(v, 0x114);   // row_shr:4
    v = dpp_min_step(v, 0x118);   // row_shr:8
    v = dpp_min_step(v, 0x142);   // row_bcast:15
    return v;                     // valid at lanes 31 and 63
}

// RNE f32 -> bf16 (bits)
__device__ inline unsigned short f2bf(float f) {
    unsigned int u = __float_as_uint(f);
    u += 0x7FFFu + ((u >> 16) & 1u);
    return (unsigned short)(u >> 16);
}
__device__ inline float bf2f(unsigned short h) {
    return __uint_as_float(((unsigned int)h) << 16);
}
// 2-way bf16 split: v ~= h + m, residual ~2^-18 rel
__device__ inline void split2(float v, unsigned short& hb, unsigned short& mb) {
    hb = f2bf(v);
    mb = f2bf(v - bf2f(hb));
}

#define ONE_BF ((short)0x3F80)

// K=16 slot maps — verbatim from the ROUND-12/16/17/19/20 VERIFIED kernels
__device__ inline void buildA2(float x0, float x1, float x2,
                               s16x8& q0, s16x8& q1) {
    float sq = fmaf(x0, x0, fmaf(x1, x1, x2 * x2));
    unsigned short uh[3], um[3], sh, sm;
    split2(-2.f * x0, uh[0], um[0]);
    split2(-2.f * x1, uh[1], um[1]);
    split2(-2.f * x2, uh[2], um[2]);
    split2(sq, sh, sm);
    q0 = (s16x8){(short)uh[0], (short)uh[1], (short)uh[2], (short)uh[0],
                 (short)uh[1], (short)uh[2], (short)um[0], (short)um[1]};
    q1 = (s16x8){(short)um[2], (short)um[0], (short)um[1], (short)um[2],
                 (short)sh, (short)sm, ONE_BF, ONE_BF};
}
__device__ inline void buildB2(float y0, float y1, float y2,
                               s16x8& q0, s16x8& q1) {
    float sq = fmaf(y0, y0, fmaf(y1, y1, y2 * y2));
    unsigned short yh[3], ym[3], sh, sm;
    split2(y0, yh[0], ym[0]);
    split2(y1, yh[1], ym[1]);
    split2(y2, yh[2], ym[2]);
    split2(sq, sh, sm);
    q0 = (s16x8){(short)yh[0], (short)yh[1], (short)yh[2], (short)ym[0],
                 (short)ym[1], (short)ym[2], (short)yh[0], (short)yh[1]};
    q1 = (s16x8){(short)yh[2], (short)ym[0], (short)ym[1], (short)ym[2],
                 ONE_BF, ONE_BF, (short)sh, (short)sm};
}

// ---------------- block reductions (4 waves, shared scratch passed in) -------

__device__ inline float blk_reduce_max(float v, float* red) {
    #pragma unroll
    for (int off = 32; off; off >>= 1) v = fmaxf(v, __shfl_xor(v, off));
    int wid = threadIdx.x >> 6;
    int lane = threadIdx.x & 63;
    if (lane == 0) red[wid] = v;
    __syncthreads();
    if (wid == 0) {
        v = (lane < 4) ? red[lane] : -3.402823466e38f;
        #pragma unroll
        for (int off = 32; off; off >>= 1) v = fmaxf(v, __shfl_xor(v, off));
        if (lane == 0) red[0] = v;
    }
    __syncthreads();
    v = red[0];
    __syncthreads();
    return v;
}

__device__ inline float blk_reduce_sum(float v, float* red) {
    #pragma unroll
    for (int off = 32; off; off >>= 1) v += __shfl_xor(v, off);
    int wid = threadIdx.x >> 6;
    int lane = threadIdx.x & 63;
    if (lane == 0) red[wid] = v;
    __syncthreads();
    if (wid == 0) {
        v = (lane < 4) ? red[lane] : 0.0f;
        #pragma unroll
        for (int off = 32; off; off >>= 1) v += __shfl_xor(v, off);
        if (lane == 0) red[0] = v;
    }
    __syncthreads();
    v = red[0];
    __syncthreads();
    return v;
}

// ---------------- kernels ----------------

// grid 192 blocks — R12/R16/R17/R19/R20-verbatim init + ctr/acc zeroing.
__global__ __launch_bounds__(256) void init_ws(const float* __restrict__ wts,
                                               const float* __restrict__ p1,
                                               const float* __restrict__ p2,
                                               unsigned int* min1, unsigned int* min2,
                                               float* __restrict__ wmax_part,
                                               unsigned int* __restrict__ ctr,
                                               s16x8* __restrict__ Afrag,
                                               s16x8* __restrict__ Bfrag,
                                               float* out) {
    int j = blockIdx.x * 256 + threadIdx.x;   // [0, B*N + B*M)
    if (j < 256) ctr[j] = 0u;                 // cntF @160, acc @168
    if (j == 0) out[0] = 0.0f;
    if (j < B_ * N_) {
        min1[j] = 0x7F7FFFFFu;                // FLT_MAX bits
        float v = wts[j];
        #pragma unroll
        for (int off = 32; off; off >>= 1) v = fmaxf(v, __shfl_xor(v, off));
        if ((j & 63) == 0) wmax_part[j >> 6] = v;   // 512 wave partials

        int b = j >> 14, n = j & (N_ - 1);
        const float* px = p1 + (size_t)j * 3;
        s16x8 q0, q1;
        buildA2(px[0], px[1], px[2], q0, q1);
        Afrag[((size_t)b * 2 + 0) * N_ + n] = q0;
        Afrag[((size_t)b * 2 + 1) * N_ + n] = q1;
    } else {
        int k = j - B_ * N_;                  // [0, B*M)
        min2[k] = 0x7F7FFFFFu;
        int b = k >> 13, m = k & (M_ - 1);
        const float* py = p2 + (size_t)k * 3;
        s16x8 q0, q1;
        buildB2(py[0], py[1], py[2], q0, q1);
        Bfrag[((size_t)b * 2 + 0) * M_ + m] = q0;
        Bfrag[((size_t)b * 2 + 1) * M_ + m] = q1;
    }
}

// ROUND-22 (= R21 resubmitted after infra failure; no kernel change):
// R20's verified kernel (39.1us, best) with CH=4 -> 8 — the same fixed-cost
// amortization lever, one more notch. Four quarter-loops share ONE
// prologue/epilogue; grid 512 = 2 blocks/CU (occupancy evidence bounds the
// risk: R0 vs R1 showed 2-vs-4 waves/SIMD is a ~3% effect here, and
// occupancy was null across five rounds). All 16 B-chunk-half loads issue in
// the prologue (regs die progressively as staged; ~140 VGPR total, fine at
// 2 waves/SIMD). Quarter body = R19/R20's verbatim sync-free 16-iter loop;
// between quarters: {barrier, combine, restage Bsh, barrier} (R20-verified
// ordering). mn1 accumulates across all 64 iterations -> single shared DPP
// epilogue. Fold math bit-identical -> absmax 0.0 expected.
__global__ __launch_bounds__(256) void chamfer_mfma(
        const s16x8* __restrict__ Afrag, const s16x8* __restrict__ Bfrag,
        unsigned int* __restrict__ min1, unsigned int* __restrict__ min2) {
    __shared__ s16x8 Bsh[4][256];        // [chunkpair*2+khalf][col] = 16KB
    __shared__ float scr[4][16][2][32];  // wave x (c*8+mt) x half x col = 16KB

    const int bid = blockIdx.x;
    const int b   = bid >> 8;            // 256 blocks per batch
    const int rr  = bid & 255;
    const int ob  = rr >> 2;             // 64 owner blocks (256 rows each)
    const int bin = rr & 3;              // 4 scan bins of 2048
    const int nb    = ob * 256;
    const int mbase = bin * (CH * 256);

    const int t = threadIdx.x;
    const int w = t >> 6, l = t & 63;
    const int lc = l & 31, lh = l >> 5;

    const s16x8* Ab = Afrag + (size_t)(b * 2) * N_;
    const s16x8* Bb = Bfrag + (size_t)(b * 2) * M_;
    unsigned int* m1g = min1 + (size_t)b * N_;
    unsigned int* m2g = min2 + (size_t)b * M_;

    // ---- prologue: ALL 16 B loads issue first; A staged via scr ----
    s16x8 b0  = Bb[0 * M_ + mbase + t];
    s16x8 b1  = Bb[1 * M_ + mbase + t];
    s16x8 b2  = Bb[0 * M_ + mbase + 256 + t];
    s16x8 b3  = Bb[1 * M_ + mbase + 256 + t];
    s16x8 b4  = Bb[0 * M_ + mbase + 512 + t];
    s16x8 b5  = Bb[1 * M_ + mbase + 512 + t];
    s16x8 b6  = Bb[0 * M_ + mbase + 768 + t];
    s16x8 b7  = Bb[1 * M_ + mbase + 768 + t];
    s16x8 b8  = Bb[0 * M_ + mbase + 1024 + t];
    s16x8 b9  = Bb[1 * M_ + mbase + 1024 + t];
    s16x8 b10 = Bb[0 * M_ + mbase + 1280 + t];
    s16x8 b11 = Bb[1 * M_ + mbase + 1280 + t];
    s16x8 b12 = Bb[0 * M_ + mbase + 1536 + t];
    s16x8 b13 = Bb[1 * M_ + mbase + 1536 + t];
    s16x8 b14 = Bb[0 * M_ + mbase + 1792 + t];
    s16x8 b15 = Bb[1 * M_ + mbase + 1792 + t];
    {
        s16x8* As = (s16x8*)scr;                // 8KB of the 16KB scr
        As[0 * 256 + t] = Ab[0 * N_ + nb + t];
        As[1 * 256 + t] = Ab[1 * N_ + nb + t];
    }
    __syncthreads();
    s16x8 Af0, Af1;
    {
        const s16x8* As = (const s16x8*)scr;
        Af0 = As[lh * 256 + w * 64 + lc];        // row-tile r0 = nb + w*64
        Af1 = As[lh * 256 + w * 64 + 32 + lc];   // row-tile r1 = +32
    }
    __syncthreads();
    Bsh[0][t] = b0;
    Bsh[1][t] = b1;
    Bsh[2][t] = b2;
    Bsh[3][t] = b3;
    __syncthreads();

    f32x16 mn1a, mn1b;
    #pragma unroll
    for (int i = 0; i < 16; i++) { mn1a[i] = 3.402823466e38f; mn1b[i] = 3.402823466e38f; }
    f32x16 zacc;
    #pragma unroll
    for (int i = 0; i < 16; i++) zacc[i] = 0.f;

    // R19/R20-verbatim sync-free 16-iteration quarter body
    #define QUARTER_BODY                                                        \
        _Pragma("unroll 2")                                                     \
        for (int it = 0; it < 16; it++) {                                       \
            const int c = it >> 3, mt = it & 7;                                 \
            s16x8 Bf = Bsh[c * 2 + lh][mt * 32 + lc];                           \
            f32x16 aA = __builtin_amdgcn_mfma_f32_32x32x16_bf16(Af0, Bf, zacc, 0, 0, 0); \
            f32x16 aB = __builtin_amdgcn_mfma_f32_32x32x16_bf16(Af1, Bf, zacc, 0, 0, 0); \
            _Pragma("unroll")                                                   \
            for (int i = 0; i < 16; i++) {                                      \
                mn1a[i] = fminf(mn1a[i], aA[i]);                                \
                mn1b[i] = fminf(mn1b[i], aB[i]);                                \
            }                                                                   \
            float f0 = min3f(aA[0], aA[1], aA[2]);                              \
            float f1 = min3f(aA[3], aA[4], aA[5]);                              \
            float f2 = min3f(aA[6], aA[7], aA[8]);                              \
            float f3 = min3f(aA[9], aA[10], aA[11]);                            \
            float f4 = min3f(aA[12], aA[13], aA[14]);                           \
            float f5 = min3f(aA[15], aB[0], aB[1]);                             \
            float f6 = min3f(aB[2], aB[3], aB[4]);                              \
            float f7 = min3f(aB[5], aB[6], aB[7]);                              \
            float f8 = min3f(aB[8], aB[9], aB[10]);                             \
            float f9 = min3f(aB[11], aB[12], aB[13]);                           \
            float g0 = min3f(f0, f1, f2);                                       \
            float g1 = min3f(f3, f4, f5);                                       \
            float g2 = min3f(f6, f7, f8);                                       \
            float g3 = min3f(f9, aB[14], aB[15]);                               \
            float m2 = fminf(fminf(g0, g1), fminf(g2, g3));                     \
            scr[w][it][lh][lc] = m2;                                            \
        }

    // R20-verified per-quarter combine (2 cols/thread, 8 reads + 1 atomic)
    #define QUARTER_COMBINE(q)                                                  \
        _Pragma("unroll")                                                       \
        for (int rep = 0; rep < 2; rep++) {                                     \
            int cid = rep * 256 + t;                                            \
            int c = cid >> 8, rem = cid & 255;                                  \
            int slot = c * 8 + (rem >> 5), cc = rem & 31;                       \
            float v = fminf(                                                    \
                fminf(fminf(scr[0][slot][0][cc], scr[0][slot][1][cc]),          \
                      fminf(scr[1][slot][0][cc], scr[1][slot][1][cc])),         \
                fminf(fminf(scr[2][slot][0][cc], scr[2][slot][1][cc]),          \
                      fminf(scr[3][slot][0][cc], scr[3][slot][1][cc])));        \
            atomicMin(&m2g[mbase + (q) * 512 + cid], __float_as_uint(v));       \
        }

    #define RESTAGE(x0, x1, x2, x3)                                             \
        Bsh[0][t] = x0; Bsh[1][t] = x1; Bsh[2][t] = x2; Bsh[3][t] = x3;         \
        __syncthreads();

    QUARTER_BODY
    __syncthreads();
    QUARTER_COMBINE(0)
    RESTAGE(b4, b5, b6, b7)

    QUARTER_BODY
    __syncthreads();
    QUARTER_COMBINE(1)
    RESTAGE(b8, b9, b10, b11)

    QUARTER_BODY
    __syncthreads();
    QUARTER_COMBINE(2)
    RESTAGE(b12, b13, b14, b15)

    QUARTER_BODY
    __syncthreads();
    QUARTER_COMBINE(3)

    #undef QUARTER_BODY
    #undef QUARTER_COMBINE
    #undef RESTAGE

    // ---- epilogue: min1 via DPP (VALU) — shared across all quarters ----
    #pragma unroll
    for (int i = 0; i < 16; i++) {
        float v = redmin32_dpp(mn1a[i]);   // valid at lanes 31 / 63
        float u = redmin32_dpp(mn1b[i]);
        if (lc == 31) {
            int row = nb + w * 64 + (i & 3) + 8 * (i >> 2) + 4 * lh;
            atomicMin(&m1g[row], __float_as_uint(v));
            atomicMin(&m1g[row + 32], __float_as_uint(u));
        }
    }
}

// ROUND-16-verbatim wide finalize (48 blocks; ticket combine proven).
__global__ __launch_bounds__(256) void finalize_wide(
        const float* __restrict__ wts,
        const unsigned int* __restrict__ min1,
        const unsigned int* __restrict__ min2,
        const float* __restrict__ wmax_part,
        unsigned int* __restrict__ ctr,
        float* __restrict__ out) {
    __shared__ float red[4];
    __shared__ unsigned tk_sh;
    unsigned int* cntF = ctr + 160;
    float* acc = (float*)(ctr + 168);    // 6 floats, zeroed by init_ws

    const int blk = blockIdx.x;
    const int t = threadIdx.x;

    if (blk < 32) {
        int b = blk >> 4, sl = blk & 15;
        float lm = wmax_part[b * 256 + t];
        float gmax = blk_reduce_max(lm, red);
        int base = b * N_ + sl * 1024;
        float se = 0.f, swm = 0.f;
        #pragma unroll
        for (int i = 0; i < 4; i++) {
            int idx = base + i * 256 + t;
            float e = expf(wts[idx] - gmax);
            se += e;
            swm += e * __uint_as_float(min1[idx]);
        }
        float tse = blk_reduce_sum(se, red);
        float tswm = blk_reduce_sum(swm, red);
        if (t == 0) {
            atomicAdd(&acc[b * 3 + 0], tse);
            atomicAdd(&acc[b * 3 + 1], tswm);
        }
    } else {
        int k = blk - 32;
        int b = k >> 3, sl = k & 7;
        int base = b * M_ + sl * 1024;
        float s = 0.f;
        #pragma unroll
        for (int i = 0; i < 4; i++)
            s += __uint_as_float(min2[base + i * 256 + t]);
        float ts = blk_reduce_sum(s, red);
        if (t == 0) atomicAdd(&acc[b * 3 + 2], ts);
    }

    // last-ticket combine (release = vmcnt(0): this wave's acc adds complete)
    asm volatile("s_waitcnt vmcnt(0)" ::: "memory");
    __syncthreads();
    if (t == 0) tk_sh = atomicAdd(cntF, 1u);
    __syncthreads();
    if (tk_sh == 47u && t == 0) {
        float s0 = atomicAdd(&acc[0], 0.0f);   // coherent RMW reads
        float s1 = atomicAdd(&acc[1], 0.0f);
        float s2 = atomicAdd(&acc[2], 0.0f);
        float s3 = atomicAdd(&acc[3], 0.0f);
        float s4 = atomicAdd(&acc[4], 0.0f);
        float s5 = atomicAdd(&acc[5], 0.0f);
        out[0] = ((s1 / s0 + s2 * (1.0f / (float)M_)) +
                  (s4 / s3 + s5 * (1.0f / (float)M_))) * (1.0f / (float)B_);
    }
}

// ---------------- launch ----------------

extern "C" void kernel_launch(void* const* d_in, const int* in_sizes, int n_in,
                              void* d_out, int out_size, void* d_ws, size_t ws_size,
                              hipStream_t stream) {
    const float* p1  = (const float*)d_in[0];  // (B, N, 3)
    const float* p2  = (const float*)d_in[1];  // (B, M, 3)
    const float* wts = (const float*)d_in[2];  // (B, N)
    float* out = (float*)d_out;

    // ws: min1 (128KB) | min2 (64KB) | wmax 512f | ctr 256u32 (pad to 4KB) |
    //     Afrag B*2*N quads (1MB) | Bfrag B*2*M quads (0.5MB)
    unsigned int* min1 = (unsigned int*)d_ws;            // B*N
    unsigned int* min2 = min1 + B_ * N_;                 // B*M
    float* wmax_part = (float*)(min2 + B_ * M_);         // 512 floats
    unsigned int* ctr = (unsigned int*)(wmax_part + 512);// 256 u32
    char* frag_base = (char*)d_ws + 196608 + 4096;       // 16B aligned
    s16x8* Afrag = (s16x8*)frag_base;                    // B*2*N quads
    s16x8* Bfrag = Afrag + B_ * 2 * N_;                  // B*2*M quads

    // 192 blocks = (B*N + B*M) / 256
    init_ws<<<dim3((B_ * N_ + B_ * M_) / 256), dim3(256), 0, stream>>>(
        wts, p1, p2, min1, min2, wmax_part, ctr, Afrag, Bfrag, out);
    // 2 batches * 64 owner-blocks * 4 scan-bins = 512 blocks (2/CU)
    chamfer_mfma<<<dim3(B_ * (N_ / 256) * (M_ / (CH * 256))), dim3(256), 0, stream>>>(
        Afrag, Bfrag, min1, min2);
    finalize_wide<<<dim3(48), dim3(256), 0, stream>>>(
        wts, min1, min2, wmax_part, ctr, out);
}